// Round 5
// baseline (230.184 us; speedup 1.0000x reference)
//
#include <hip/hip_runtime.h>
#include <math.h>

#define G 1200
#define NIN 10
#define NHE 300
#define NINC 4800
#define ALPHA 0.005f
#define BETA 5e-5f
#define BN_EPS 1e-5f
#define NBLK 1024
#define NTHR 256
#define NSTRIPE 16
#define STRIDE_I 32  // ints per stripe (128 B spacing)

struct Params {
    const float *x, *edge1, *edge2, *W1, *b1, *infer_w, *infer_b;
    const float *e1w, *e1b, *e2w, *e2b;
    const float *n1w, *n1b, *n2w, *n2b;
    const float *m1w, *m1b, *m2w, *m2b, *m3w, *m3b;
    const float *hgw, *hgb;
    const int *hn, *he;
    float4 *xfeat1, *xfeat2, *upd2;
    float *a1, *c1, *a2, *c2, *efeat;
    int *eh;
    int *bar;        // 3 phases x 16 stripes x 32 ints, zeroed by memset node
    float4 *out;
};

__device__ __forceinline__ float eluf(float x) { return x > 0.f ? x : __expf(x) - 1.f; }
__device__ __forceinline__ float sigf(float x) { return 1.f / (1.f + __expf(-x)); }
__device__ __forceinline__ float wred(float v) {
#pragma unroll
    for (int o = 32; o > 0; o >>= 1) v += __shfl_down(v, o, 64);
    return v;
}

// Striped device-wide barrier. All NBLK blocks must be co-resident
// (guaranteed: VGPR<=64 via launch_bounds -> capacity 2048 blocks > 1024).
__device__ void gridbar(int* bar, int phase, int blk, int tid) {
    __syncthreads();
    if (tid == 0) {
        __threadfence();  // release: my phase writes visible device-wide
        int* base = bar + phase * NSTRIPE * STRIDE_I;
        atomicAdd(base + (blk & (NSTRIPE - 1)) * STRIDE_I, 1);
        for (long it = 0; it < (2l << 20); ++it) {  // bounded spin (safety valve)
            int s = 0;
#pragma unroll
            for (int k = 0; k < NSTRIPE; ++k)
                s += __hip_atomic_load(base + k * STRIDE_I, __ATOMIC_RELAXED,
                                       __HIP_MEMORY_SCOPE_AGENT);
            if (s >= NBLK) break;
        }
        __threadfence();  // acquire
    }
    __syncthreads();
}

// Round body (proven in the 46us chain): block handles gene i, wave w = batch.
// MODE 1: round1 -> elu(z*W1diag+b1) -> BN -> xfeat2 + gate terms a2,c2.
// MODE 2: round2 -> BN -> upd2; scatter sum_b hgw@upd2[b,i] into efeat/eh.
template <int MODE>
__device__ void round_pass(const Params& p, int blk, int tid,
                           const float* __restrict__ edge, float coef,
                           const float4* __restrict__ xfeat,
                           const float* __restrict__ a, const float* __restrict__ c,
                           const float* __restrict__ nw, const float* __restrict__ nb,
                           const float* __restrict__ mw, const float* __restrict__ mb,
                           float4* __restrict__ out_feat,
                           float* __restrict__ a_out, float* __restrict__ c_out) {
    const int lane = tid & 63;
    const int w = tid >> 6;  // wave index == batch index
    __shared__ float t[4][5];
    __shared__ float hvs[4][4];
    __shared__ float stats[2];
    __shared__ float bsf[4];

    for (int i = blk; i < G; i += NBLK) {
        const float* erow = edge + (size_t)i * G;
        const float cb = c[w * G + i];
        float acc0 = 0.f, acc1 = 0.f, acc2 = 0.f, acc3 = 0.f, acc4 = 0.f;
        for (int j = lane; j < G; j += 64) {
            float m = erow[j];
            float mask = (m == 0.f) ? coef : m;  // edge + coef*(edge==0)
            float4 xj = xfeat[w * G + j];
            float sg = sigf(a[w * G + j] + cb) * mask;
            acc0 += sg * xj.x;
            acc1 += sg * xj.y;
            acc2 += sg * xj.z;
            acc3 += sg * xj.w;
            acc4 += sg;
        }
        acc0 = wred(acc0); acc1 = wred(acc1); acc2 = wred(acc2);
        acc3 = wred(acc3); acc4 = wred(acc4);
        if (lane == 0) {
            t[w][0] = acc0; t[w][1] = acc1; t[w][2] = acc2; t[w][3] = acc3; t[w][4] = acc4;
        }
        __syncthreads();

        if (tid < 4) {
            const int b = tid;
            float4 xi4 = xfeat[b * G + i];
            float xi[4] = {xi4.x, xi4.y, xi4.z, xi4.w};
            float ssum = t[b][4];
            float r8[8];
#pragma unroll
            for (int k = 0; k < 4; ++k) { r8[k] = t[b][k]; r8[4 + k] = xi[k] * ssum; }
            float r[4];
#pragma unroll
            for (int f = 0; f < 4; ++f) {
                float sv = nb[f];
#pragma unroll
                for (int k = 0; k < 8; ++k) sv += nw[f * 8 + k] * r8[k];
                r[f] = eluf(sv);
            }
            float w1d = 0.f, b1i = 0.f;
            if (MODE == 1) { w1d = p.W1[(size_t)i * G + i]; b1i = p.b1[i]; }
#pragma unroll
            for (int f = 0; f < 4; ++f) {
                float sv = mb[f];
#pragma unroll
                for (int k = 0; k < 4; ++k) sv += mw[f * 8 + k] * r[k] + mw[f * 8 + 4 + k] * xi[k];
                float z = eluf(sv);
                hvs[b][f] = (MODE == 1) ? eluf(z * w1d + b1i) : z;
            }
        }
        __syncthreads();

        if (tid == 0) {  // BN per gene over (batch, feat): 16 values
            float mean = 0.f;
#pragma unroll
            for (int bb = 0; bb < 4; ++bb)
#pragma unroll
                for (int f = 0; f < 4; ++f) mean += hvs[bb][f];
            mean *= (1.f / 16.f);
            float var = 0.f;
#pragma unroll
            for (int bb = 0; bb < 4; ++bb)
#pragma unroll
                for (int f = 0; f < 4; ++f) { float d = hvs[bb][f] - mean; var += d * d; }
            var *= (1.f / 16.f);
            stats[0] = mean;
            stats[1] = rsqrtf(var + BN_EPS);
        }
        __syncthreads();

        if (tid < 4) {
            const int b = tid;
            const float mean = stats[0], sc = stats[1];
            float hv[4];
#pragma unroll
            for (int f = 0; f < 4; ++f) hv[f] = (hvs[b][f] - mean) * sc;
            out_feat[b * G + i] = make_float4(hv[0], hv[1], hv[2], hv[3]);
            if (MODE == 1) {
                float av = 0.f, cv = 0.f;
#pragma unroll
                for (int f = 0; f < 4; ++f) { av += p.e2w[f] * hv[f]; cv += p.e2w[4 + f] * hv[f]; }
                a_out[b * G + i] = av;
                c_out[b * G + i] = cv + p.e2b[0];
            } else {
                hvs[b][0] = hv[0]; hvs[b][1] = hv[1]; hvs[b][2] = hv[2]; hvs[b][3] = hv[3];
            }
        }

        if (MODE == 2) {
            __syncthreads();
            if (tid < 4) {
                const int f = tid;
                float sv = 0.f;
#pragma unroll
                for (int bb = 0; bb < 4; ++bb)
#pragma unroll
                    for (int k = 0; k < 4; ++k) sv += p.hgw[f * 4 + k] * hvs[bb][k];
                bsf[f] = sv;
            }
            __syncthreads();
            const float v0 = bsf[0], v1 = bsf[1], v2 = bsf[2], v3 = bsf[3];
            for (int cI = tid; cI < NINC; cI += NTHR) {
                if (p.hn[cI] == i) {
                    int e = p.he[cI];
                    atomicAdd(&p.eh[e], 1);
                    atomicAdd(&p.efeat[e * 4 + 0], v0);
                    atomicAdd(&p.efeat[e * 4 + 1], v1);
                    atomicAdd(&p.efeat[e * 4 + 2], v2);
                    atomicAdd(&p.efeat[e * 4 + 3], v3);
                }
            }
        }
        __syncthreads();  // protect LDS reuse across gene iterations
    }
}

__device__ void final_pass(const Params& p, int blk, int tid) {
    const int lane = tid & 63;
    const int w = tid >> 6;
    __shared__ float red[4][5];

    for (int i = blk; i < G; i += NBLK) {
        float a0 = 0.f, a1 = 0.f, a2 = 0.f, a3 = 0.f, cf = 0.f;
        for (int cI = tid; cI < NINC; cI += NTHR) {
            if (p.hn[cI] == i) {
                int e = p.he[cI];
                float binv = 0.25f / (float)p.eh[e];  // bdeg = BSZ * hist(edges)
                a0 += p.efeat[e * 4 + 0] * binv;
                a1 += p.efeat[e * 4 + 1] * binv;
                a2 += p.efeat[e * 4 + 2] * binv;
                a3 += p.efeat[e * 4 + 3] * binv;
                cf += 1.f;
            }
        }
        a0 = wred(a0); a1 = wred(a1); a2 = wred(a2); a3 = wred(a3); cf = wred(cf);
        if (lane == 0) { red[w][0] = a0; red[w][1] = a1; red[w][2] = a2; red[w][3] = a3; red[w][4] = cf; }
        __syncthreads();

        if (tid < 4) {
            const int b = tid;
            float dg = red[0][4] + red[1][4] + red[2][4] + red[3][4];
            float dinv = dg > 0.f ? 1.f / dg : 0.f;
            float hxp[4];
#pragma unroll
            for (int f = 0; f < 4; ++f) {
                float hx = (red[0][f] + red[1][f] + red[2][f] + red[3][f]) * dinv;
                hxp[f] = eluf(hx + p.hgb[f]);
            }
            float4 u4 = p.upd2[b * G + i];
            float u[4] = {u4.x, u4.y, u4.z, u4.w};
            float o4[4];
#pragma unroll
            for (int f = 0; f < 4; ++f) {
                float sv = p.m3b[f];
#pragma unroll
                for (int k = 0; k < 4; ++k)
                    sv += p.m3w[f * 8 + k] * u[k] + p.m3w[f * 8 + 4 + k] * hxp[k];
                o4[f] = eluf(sv);
            }
            p.out[b * G + i] = make_float4(o4[0], o4[1], o4[2], o4[3]);
        }
        __syncthreads();
    }
}

__global__ __launch_bounds__(NTHR, 8)
void mega_kernel(Params p) {
    const int blk = blockIdx.x, tid = threadIdx.x;

    // Phase A: infer on blocks 0..18 (4864 threads cover 4800 nodes); block 19 zeros efeat/eh.
    if (blk < 19) {
        const int n = blk * NTHR + tid;
        if (n < 4 * G) {
            const float* xp = p.x + n * NIN;
            float h[4];
#pragma unroll
            for (int f = 0; f < 4; ++f) {
                float sv = p.infer_b[f];
#pragma unroll
                for (int k = 0; k < NIN; ++k) sv += p.infer_w[f * NIN + k] * xp[k];
                h[f] = eluf(sv);
            }
            p.xfeat1[n] = make_float4(h[0], h[1], h[2], h[3]);
            float av = 0.f, cv = 0.f;
#pragma unroll
            for (int f = 0; f < 4; ++f) { av += p.e1w[f] * h[f]; cv += p.e1w[4 + f] * h[f]; }
            p.a1[n] = av;
            p.c1[n] = cv + p.e1b[0];
        }
    } else if (blk == 19) {
        for (int q = tid; q < NHE * 4; q += NTHR) p.efeat[q] = 0.f;
        for (int q = tid; q < NHE; q += NTHR) p.eh[q] = 0;
    }
    gridbar(p.bar, 0, blk, tid);

    round_pass<1>(p, blk, tid, p.edge1, ALPHA, p.xfeat1, p.a1, p.c1,
                  p.n1w, p.n1b, p.m1w, p.m1b, p.xfeat2, p.a2, p.c2);
    gridbar(p.bar, 1, blk, tid);

    round_pass<2>(p, blk, tid, p.edge2, BETA, p.xfeat2, p.a2, p.c2,
                  p.n2w, p.n2b, p.m2w, p.m2b, p.upd2, nullptr, nullptr);
    gridbar(p.bar, 2, blk, tid);

    final_pass(p, blk, tid);
}

extern "C" void kernel_launch(void* const* d_in, const int* in_sizes, int n_in,
                              void* d_out, int out_size, void* d_ws, size_t ws_size,
                              hipStream_t stream) {
    Params p;
    p.x       = (const float*)d_in[0];
    p.edge1   = (const float*)d_in[1];
    p.edge2   = (const float*)d_in[2];
    p.W1      = (const float*)d_in[3];
    p.b1      = (const float*)d_in[4];
    p.infer_w = (const float*)d_in[5];
    p.infer_b = (const float*)d_in[6];
    p.e1w     = (const float*)d_in[7];
    p.e1b     = (const float*)d_in[8];
    p.e2w     = (const float*)d_in[9];
    p.e2b     = (const float*)d_in[10];
    p.n1w     = (const float*)d_in[11];
    p.n1b     = (const float*)d_in[12];
    p.n2w     = (const float*)d_in[13];
    p.n2b     = (const float*)d_in[14];
    p.m1w     = (const float*)d_in[15];
    p.m1b     = (const float*)d_in[16];
    p.m2w     = (const float*)d_in[17];
    p.m2b     = (const float*)d_in[18];
    p.m3w     = (const float*)d_in[19];
    p.m3b     = (const float*)d_in[20];
    p.hgw     = (const float*)d_in[21];
    p.hgb     = (const float*)d_in[22];
    p.hn      = (const int*)d_in[23];
    p.he      = (const int*)d_in[24];

    char* ws = (char*)d_ws;
    p.xfeat1 = (float4*)(ws + 0);        // 76800
    p.xfeat2 = (float4*)(ws + 76800);    // 76800
    p.upd2   = (float4*)(ws + 153600);   // 76800
    p.a1     = (float*)(ws + 230400);    // 19200
    p.c1     = (float*)(ws + 249600);    // 19200
    p.a2     = (float*)(ws + 268800);    // 19200
    p.c2     = (float*)(ws + 288000);    // 19200
    p.efeat  = (float*)(ws + 307200);    // 4800
    p.eh     = (int*)(ws + 312000);      // 1200
    p.bar    = (int*)(ws + 313344);      // 3*16*32*4 = 6144, 128B-aligned
    p.out    = (float4*)d_out;

    hipMemsetAsync(ws + 313344, 0, 3 * NSTRIPE * STRIDE_I * sizeof(int), stream);
    mega_kernel<<<NBLK, NTHR, 0, stream>>>(p);
}

// Round 6
// 161.995 us; speedup vs baseline: 1.4209x; 1.4209x over previous
//
#include <hip/hip_runtime.h>
#include <math.h>

#define G 1200
#define NIN 10
#define NHE 300
#define NINC 4800
#define ALPHA 0.005f
#define BETA 5e-5f
#define BN_EPS 1e-5f

__device__ __forceinline__ float eluf(float x) { return x > 0.f ? x : __expf(x) - 1.f; }
__device__ __forceinline__ float sigf(float x) { return 1.f / (1.f + __expf(-x)); }
__device__ __forceinline__ float wred(float v) {
#pragma unroll
    for (int o = 32; o > 0; o >>= 1) v += __shfl_down(v, o, 64);
    return v;
}
__device__ __forceinline__ float maskf(float e, float coef) { return (e == 0.f) ? coef : e; }

// ---------------- K1: fused infer + round1. 600 blocks, 2 genes each (i, i+600).
// Wave w = batch. h_j = elu(infer(x_j)) computed on the fly (x is L2-resident).
__global__ __launch_bounds__(256)
void k_round1(const float* __restrict__ x,
              const float* __restrict__ edge1,
              const float* __restrict__ W1, const float* __restrict__ b1,
              const float* __restrict__ iw, const float* __restrict__ ib,
              const float* __restrict__ e1w, const float* __restrict__ e1b,
              const float* __restrict__ n1w, const float* __restrict__ n1b,
              const float* __restrict__ m1w, const float* __restrict__ m1b,
              const float* __restrict__ e2w, const float* __restrict__ e2b,
              float4* __restrict__ xfeat2, float* __restrict__ a2, float* __restrict__ c2) {
    const int tid = threadIdx.x;
    const int lane = tid & 63;
    const int w = tid >> 6;  // batch
    const int i0 = blockIdx.x, i1 = blockIdx.x + 600;

    // own-gene features (uniform within wave; redundant per lane, cheap)
    float hi0[4], hi1[4];
    {
        const float* xp0 = x + ((size_t)w * G + i0) * NIN;
        const float* xp1 = x + ((size_t)w * G + i1) * NIN;
#pragma unroll
        for (int f = 0; f < 4; ++f) {
            float s0 = ib[f], s1 = ib[f];
#pragma unroll
            for (int k = 0; k < NIN; ++k) { s0 += iw[f * NIN + k] * xp0[k]; s1 += iw[f * NIN + k] * xp1[k]; }
            hi0[f] = eluf(s0);
            hi1[f] = eluf(s1);
        }
    }
    const float cb0 = e1w[4] * hi0[0] + e1w[5] * hi0[1] + e1w[6] * hi0[2] + e1w[7] * hi0[3] + e1b[0];
    const float cb1 = e1w[4] * hi1[0] + e1w[5] * hi1[1] + e1w[6] * hi1[2] + e1w[7] * hi1[3] + e1b[0];

    const float4* r0 = (const float4*)(edge1 + (size_t)i0 * G);
    const float4* r1 = (const float4*)(edge1 + (size_t)i1 * G);

    float acc[10];
#pragma unroll
    for (int k = 0; k < 10; ++k) acc[k] = 0.f;

    for (int m = lane; m < 300; m += 64) {
        float e0a[4], e1a[4];
        *(float4*)e0a = r0[m];
        *(float4*)e1a = r1[m];
        float xf[40];
        const float* xp = x + ((size_t)w * G + 4 * m) * NIN;
#pragma unroll
        for (int q = 0; q < 10; ++q) *(float4*)&xf[4 * q] = ((const float4*)xp)[q];
#pragma unroll
        for (int s = 0; s < 4; ++s) {
            float h[4];
#pragma unroll
            for (int f = 0; f < 4; ++f) {
                float sv = ib[f];
#pragma unroll
                for (int k = 0; k < NIN; ++k) sv += iw[f * NIN + k] * xf[10 * s + k];
                h[f] = eluf(sv);
            }
            float aj = e1w[0] * h[0] + e1w[1] * h[1] + e1w[2] * h[2] + e1w[3] * h[3];
            float sg0 = sigf(aj + cb0) * maskf(e0a[s], ALPHA);
            float sg1 = sigf(aj + cb1) * maskf(e1a[s], ALPHA);
            acc[0] += sg0 * h[0]; acc[1] += sg0 * h[1]; acc[2] += sg0 * h[2];
            acc[3] += sg0 * h[3]; acc[4] += sg0;
            acc[5] += sg1 * h[0]; acc[6] += sg1 * h[1]; acc[7] += sg1 * h[2];
            acc[8] += sg1 * h[3]; acc[9] += sg1;
        }
    }
#pragma unroll
    for (int k = 0; k < 10; ++k) acc[k] = wred(acc[k]);

    __shared__ float t[2][4][5];
    __shared__ float him[2][4][4];
    __shared__ float hvs[2][4][4];
    __shared__ float stats[2][2];

    if (lane == 0) {
#pragma unroll
        for (int k = 0; k < 5; ++k) { t[0][w][k] = acc[k]; t[1][w][k] = acc[5 + k]; }
#pragma unroll
        for (int f = 0; f < 4; ++f) { him[0][w][f] = hi0[f]; him[1][w][f] = hi1[f]; }
    }
    __syncthreads();

    if (tid < 8) {
        const int b = tid & 3, g = tid >> 2;
        const int i = (g == 0) ? i0 : i1;
        float xi[4] = {him[g][b][0], him[g][b][1], him[g][b][2], him[g][b][3]};
        float ssum = t[g][b][4];
        float r8[8];
#pragma unroll
        for (int k = 0; k < 4; ++k) { r8[k] = t[g][b][k]; r8[4 + k] = xi[k] * ssum; }
        float r[4];
#pragma unroll
        for (int f = 0; f < 4; ++f) {
            float sv = n1b[f];
#pragma unroll
            for (int k = 0; k < 8; ++k) sv += n1w[f * 8 + k] * r8[k];
            r[f] = eluf(sv);
        }
        const float w1d = W1[(size_t)i * G + i], b1i = b1[i];
#pragma unroll
        for (int f = 0; f < 4; ++f) {
            float sv = m1b[f];
#pragma unroll
            for (int k = 0; k < 4; ++k) sv += m1w[f * 8 + k] * r[k] + m1w[f * 8 + 4 + k] * xi[k];
            hvs[g][b][f] = eluf(eluf(sv) * w1d + b1i);
        }
    }
    __syncthreads();

    if (tid < 2) {  // BN per gene over (batch, feat) = 16 values
        const int g = tid;
        float mean = 0.f;
#pragma unroll
        for (int bb = 0; bb < 4; ++bb)
#pragma unroll
            for (int f = 0; f < 4; ++f) mean += hvs[g][bb][f];
        mean *= (1.f / 16.f);
        float var = 0.f;
#pragma unroll
        for (int bb = 0; bb < 4; ++bb)
#pragma unroll
            for (int f = 0; f < 4; ++f) { float d = hvs[g][bb][f] - mean; var += d * d; }
        var *= (1.f / 16.f);
        stats[g][0] = mean;
        stats[g][1] = rsqrtf(var + BN_EPS);
    }
    __syncthreads();

    if (tid < 8) {
        const int b = tid & 3, g = tid >> 2;
        const int i = (g == 0) ? i0 : i1;
        const float mean = stats[g][0], sc = stats[g][1];
        float hv[4];
#pragma unroll
        for (int f = 0; f < 4; ++f) hv[f] = (hvs[g][b][f] - mean) * sc;
        xfeat2[b * G + i] = make_float4(hv[0], hv[1], hv[2], hv[3]);
        a2[b * G + i] = e2w[0] * hv[0] + e2w[1] * hv[1] + e2w[2] * hv[2] + e2w[3] * hv[3];
        c2[b * G + i] = e2w[4] * hv[0] + e2w[5] * hv[1] + e2w[6] * hv[2] + e2w[7] * hv[3] + e2b[0];
    }
}

// ---------------- K2: round2. 1200 blocks, gene i = blockIdx. Writes upd2 + bs[i].
__global__ __launch_bounds__(256)
void k_round2(const float* __restrict__ edge2,
              const float4* __restrict__ xfeat2,
              const float* __restrict__ a2, const float* __restrict__ c2,
              const float* __restrict__ n2w, const float* __restrict__ n2b,
              const float* __restrict__ m2w, const float* __restrict__ m2b,
              const float* __restrict__ hgw,
              float4* __restrict__ upd2, float* __restrict__ bs) {
    const int i = blockIdx.x;
    const int tid = threadIdx.x;
    const int lane = tid & 63;
    const int w = tid >> 6;

    const float cb = c2[w * G + i];
    const float4* erow4 = (const float4*)(edge2 + (size_t)i * G);
    const float4* a4 = (const float4*)(a2 + (size_t)w * G);

    float acc0 = 0.f, acc1 = 0.f, acc2 = 0.f, acc3 = 0.f, acc4 = 0.f;
    for (int m = lane; m < 300; m += 64) {
        float ea[4], aa[4];
        *(float4*)ea = erow4[m];
        *(float4*)aa = a4[m];
#pragma unroll
        for (int s = 0; s < 4; ++s) {
            float4 xv = xfeat2[w * G + 4 * m + s];
            float sg = sigf(aa[s] + cb) * maskf(ea[s], BETA);
            acc0 += sg * xv.x;
            acc1 += sg * xv.y;
            acc2 += sg * xv.z;
            acc3 += sg * xv.w;
            acc4 += sg;
        }
    }
    acc0 = wred(acc0); acc1 = wred(acc1); acc2 = wred(acc2); acc3 = wred(acc3); acc4 = wred(acc4);

    __shared__ float t[4][5];
    __shared__ float hvs[4][4];
    __shared__ float stats[2];
    if (lane == 0) { t[w][0] = acc0; t[w][1] = acc1; t[w][2] = acc2; t[w][3] = acc3; t[w][4] = acc4; }
    __syncthreads();

    if (tid < 4) {
        const int b = tid;
        float4 xi4 = xfeat2[b * G + i];
        float xi[4] = {xi4.x, xi4.y, xi4.z, xi4.w};
        float ssum = t[b][4];
        float r8[8];
#pragma unroll
        for (int k = 0; k < 4; ++k) { r8[k] = t[b][k]; r8[4 + k] = xi[k] * ssum; }
        float r[4];
#pragma unroll
        for (int f = 0; f < 4; ++f) {
            float sv = n2b[f];
#pragma unroll
            for (int k = 0; k < 8; ++k) sv += n2w[f * 8 + k] * r8[k];
            r[f] = eluf(sv);
        }
#pragma unroll
        for (int f = 0; f < 4; ++f) {
            float sv = m2b[f];
#pragma unroll
            for (int k = 0; k < 4; ++k) sv += m2w[f * 8 + k] * r[k] + m2w[f * 8 + 4 + k] * xi[k];
            hvs[b][f] = eluf(sv);
        }
    }
    __syncthreads();

    if (tid == 0) {
        float mean = 0.f;
#pragma unroll
        for (int bb = 0; bb < 4; ++bb)
#pragma unroll
            for (int f = 0; f < 4; ++f) mean += hvs[bb][f];
        mean *= (1.f / 16.f);
        float var = 0.f;
#pragma unroll
        for (int bb = 0; bb < 4; ++bb)
#pragma unroll
            for (int f = 0; f < 4; ++f) { float d = hvs[bb][f] - mean; var += d * d; }
        var *= (1.f / 16.f);
        stats[0] = mean;
        stats[1] = rsqrtf(var + BN_EPS);
    }
    __syncthreads();

    if (tid < 4) {
        const int b = tid;
        const float mean = stats[0], sc = stats[1];
        float hv[4];
#pragma unroll
        for (int f = 0; f < 4; ++f) hv[f] = (hvs[b][f] - mean) * sc;
        upd2[b * G + i] = make_float4(hv[0], hv[1], hv[2], hv[3]);
        hvs[b][0] = hv[0]; hvs[b][1] = hv[1]; hvs[b][2] = hv[2]; hvs[b][3] = hv[3];
    }
    __syncthreads();

    if (tid < 4) {  // bs[i][f] = sum_b hgw[f,:] @ hvs[b,:]
        const int f = tid;
        float sv = 0.f;
#pragma unroll
        for (int bb = 0; bb < 4; ++bb)
#pragma unroll
            for (int k = 0; k < 4; ++k) sv += hgw[f * 4 + k] * hvs[bb][k];
        bs[i * 4 + f] = sv;
    }
}

// ---------------- K3: hypergraph (batch-degenerate) via per-block LDS efeat/eh + final MLP.
__global__ __launch_bounds__(256)
void k_final(const int* __restrict__ hn, const int* __restrict__ he,
             const float* __restrict__ bs,
             const float4* __restrict__ upd2, const float* __restrict__ hgb,
             const float* __restrict__ m3w, const float* __restrict__ m3b,
             float4* __restrict__ out) {
    const int i = blockIdx.x;
    const int tid = threadIdx.x;
    const int lane = tid & 63;
    const int w = tid >> 6;

    __shared__ float ef[NHE][4];
    __shared__ int eh[NHE];
    __shared__ float red[4][5];

    for (int t = tid; t < NHE; t += 256) {
        eh[t] = 0;
        ef[t][0] = ef[t][1] = ef[t][2] = ef[t][3] = 0.f;
    }
    __syncthreads();

    const float4* bs4 = (const float4*)bs;
    for (int cI = tid; cI < NINC; cI += 256) {
        int n = hn[cI], e = he[cI];
        float4 bv = bs4[n];
        atomicAdd(&eh[e], 1);
        atomicAdd(&ef[e][0], bv.x);
        atomicAdd(&ef[e][1], bv.y);
        atomicAdd(&ef[e][2], bv.z);
        atomicAdd(&ef[e][3], bv.w);
    }
    __syncthreads();

    float a0 = 0.f, a1 = 0.f, a2 = 0.f, a3 = 0.f, cf = 0.f;
    for (int cI = tid; cI < NINC; cI += 256) {
        if (hn[cI] == i) {
            int e = he[cI];
            float binv = 0.25f / (float)eh[e];  // bdeg = BSZ * hist
            a0 += ef[e][0] * binv;
            a1 += ef[e][1] * binv;
            a2 += ef[e][2] * binv;
            a3 += ef[e][3] * binv;
            cf += 1.f;
        }
    }
    a0 = wred(a0); a1 = wred(a1); a2 = wred(a2); a3 = wred(a3); cf = wred(cf);
    if (lane == 0) { red[w][0] = a0; red[w][1] = a1; red[w][2] = a2; red[w][3] = a3; red[w][4] = cf; }
    __syncthreads();

    if (tid < 4) {
        const int b = tid;
        float dg = red[0][4] + red[1][4] + red[2][4] + red[3][4];
        float dinv = dg > 0.f ? 1.f / dg : 0.f;
        float hxp[4];
#pragma unroll
        for (int f = 0; f < 4; ++f) {
            float hx = (red[0][f] + red[1][f] + red[2][f] + red[3][f]) * dinv;
            hxp[f] = eluf(hx + hgb[f]);
        }
        float4 u4 = upd2[b * G + i];
        float u[4] = {u4.x, u4.y, u4.z, u4.w};
        float o4[4];
#pragma unroll
        for (int f = 0; f < 4; ++f) {
            float sv = m3b[f];
#pragma unroll
            for (int k = 0; k < 4; ++k)
                sv += m3w[f * 8 + k] * u[k] + m3w[f * 8 + 4 + k] * hxp[k];
            o4[f] = eluf(sv);
        }
        out[b * G + i] = make_float4(o4[0], o4[1], o4[2], o4[3]);
    }
}

extern "C" void kernel_launch(void* const* d_in, const int* in_sizes, int n_in,
                              void* d_out, int out_size, void* d_ws, size_t ws_size,
                              hipStream_t stream) {
    const float* x       = (const float*)d_in[0];
    const float* edge1   = (const float*)d_in[1];
    const float* edge2   = (const float*)d_in[2];
    const float* W1      = (const float*)d_in[3];
    const float* b1      = (const float*)d_in[4];
    const float* infer_w = (const float*)d_in[5];
    const float* infer_b = (const float*)d_in[6];
    const float* e1w     = (const float*)d_in[7];
    const float* e1b     = (const float*)d_in[8];
    const float* e2w     = (const float*)d_in[9];
    const float* e2b     = (const float*)d_in[10];
    const float* n1w     = (const float*)d_in[11];
    const float* n1b     = (const float*)d_in[12];
    const float* n2w     = (const float*)d_in[13];
    const float* n2b     = (const float*)d_in[14];
    const float* m1w     = (const float*)d_in[15];
    const float* m1b     = (const float*)d_in[16];
    const float* m2w     = (const float*)d_in[17];
    const float* m2b     = (const float*)d_in[18];
    const float* m3w     = (const float*)d_in[19];
    const float* m3b     = (const float*)d_in[20];
    const float* hgw     = (const float*)d_in[21];
    const float* hgb     = (const float*)d_in[22];
    const int*   hn      = (const int*)d_in[23];
    const int*   he      = (const int*)d_in[24];

    char* ws = (char*)d_ws;
    float4* xfeat2 = (float4*)(ws + 0);       // 76800
    float4* upd2   = (float4*)(ws + 76800);   // 76800
    float*  a2     = (float*)(ws + 153600);   // 19200
    float*  c2     = (float*)(ws + 172800);   // 19200
    float*  bs     = (float*)(ws + 192000);   // 19200

    k_round1<<<600, 256, 0, stream>>>(x, edge1, W1, b1, infer_w, infer_b, e1w, e1b,
                                      n1w, n1b, m1w, m1b, e2w, e2b, xfeat2, a2, c2);
    k_round2<<<1200, 256, 0, stream>>>(edge2, xfeat2, a2, c2, n2w, n2b, m2w, m2b, hgw,
                                       upd2, bs);
    k_final<<<1200, 256, 0, stream>>>(hn, he, bs, upd2, hgb, m3w, m3b, (float4*)d_out);
}

// Round 7
// 47.302 us; speedup vs baseline: 4.8662x; 3.4247x over previous
//
#include <hip/hip_runtime.h>
#include <math.h>

#define G 1200
#define NIN 10
#define NHE 300
#define NINC 4800
#define ALPHA 0.005f
#define BETA 5e-5f
#define BN_EPS 1e-5f

__device__ __forceinline__ float eluf(float x) { return x > 0.f ? x : __expf(x) - 1.f; }
__device__ __forceinline__ float sigf(float x) { return 1.f / (1.f + __expf(-x)); }
__device__ __forceinline__ float wred(float v) {
#pragma unroll
    for (int o = 32; o > 0; o >>= 1) v += __shfl_down(v, o, 64);
    return v;
}
__device__ __forceinline__ float maskf(float e, float coef) { return (e == 0.f) ? coef : e; }

// ---------------- K1: fused infer + round1. 600 blocks, 2 genes each (i, i+600).
// Wave w = batch. h_j = elu(infer(x_j)) computed on the fly (x is L2-resident).
// Block 0 additionally zeros the global efeat/eh accumulators (1500 words).
__global__ __launch_bounds__(256)
void k_round1(const float* __restrict__ x,
              const float* __restrict__ edge1,
              const float* __restrict__ W1, const float* __restrict__ b1,
              const float* __restrict__ iw, const float* __restrict__ ib,
              const float* __restrict__ e1w, const float* __restrict__ e1b,
              const float* __restrict__ n1w, const float* __restrict__ n1b,
              const float* __restrict__ m1w, const float* __restrict__ m1b,
              const float* __restrict__ e2w, const float* __restrict__ e2b,
              float4* __restrict__ xfeat2, float* __restrict__ a2, float* __restrict__ c2,
              int* __restrict__ zero_region) {
    const int tid = threadIdx.x;
    const int lane = tid & 63;
    const int w = tid >> 6;  // batch
    const int i0 = blockIdx.x, i1 = blockIdx.x + 600;

    if (blockIdx.x == 0) {
        for (int t = tid; t < NHE * 4 + NHE; t += 256) zero_region[t] = 0;
    }

    // own-gene features (uniform within wave; redundant per lane, cheap)
    float hi0[4], hi1[4];
    {
        const float* xp0 = x + ((size_t)w * G + i0) * NIN;
        const float* xp1 = x + ((size_t)w * G + i1) * NIN;
#pragma unroll
        for (int f = 0; f < 4; ++f) {
            float s0 = ib[f], s1 = ib[f];
#pragma unroll
            for (int k = 0; k < NIN; ++k) { s0 += iw[f * NIN + k] * xp0[k]; s1 += iw[f * NIN + k] * xp1[k]; }
            hi0[f] = eluf(s0);
            hi1[f] = eluf(s1);
        }
    }
    const float cb0 = e1w[4] * hi0[0] + e1w[5] * hi0[1] + e1w[6] * hi0[2] + e1w[7] * hi0[3] + e1b[0];
    const float cb1 = e1w[4] * hi1[0] + e1w[5] * hi1[1] + e1w[6] * hi1[2] + e1w[7] * hi1[3] + e1b[0];

    const float4* r0 = (const float4*)(edge1 + (size_t)i0 * G);
    const float4* r1 = (const float4*)(edge1 + (size_t)i1 * G);

    float acc[10];
#pragma unroll
    for (int k = 0; k < 10; ++k) acc[k] = 0.f;

    for (int m = lane; m < 300; m += 64) {
        float e0a[4], e1a[4];
        *(float4*)e0a = r0[m];
        *(float4*)e1a = r1[m];
        float xf[40];
        const float* xp = x + ((size_t)w * G + 4 * m) * NIN;
#pragma unroll
        for (int q = 0; q < 10; ++q) *(float4*)&xf[4 * q] = ((const float4*)xp)[q];
#pragma unroll
        for (int s = 0; s < 4; ++s) {
            float h[4];
#pragma unroll
            for (int f = 0; f < 4; ++f) {
                float sv = ib[f];
#pragma unroll
                for (int k = 0; k < NIN; ++k) sv += iw[f * NIN + k] * xf[10 * s + k];
                h[f] = eluf(sv);
            }
            float aj = e1w[0] * h[0] + e1w[1] * h[1] + e1w[2] * h[2] + e1w[3] * h[3];
            float sg0 = sigf(aj + cb0) * maskf(e0a[s], ALPHA);
            float sg1 = sigf(aj + cb1) * maskf(e1a[s], ALPHA);
            acc[0] += sg0 * h[0]; acc[1] += sg0 * h[1]; acc[2] += sg0 * h[2];
            acc[3] += sg0 * h[3]; acc[4] += sg0;
            acc[5] += sg1 * h[0]; acc[6] += sg1 * h[1]; acc[7] += sg1 * h[2];
            acc[8] += sg1 * h[3]; acc[9] += sg1;
        }
    }
#pragma unroll
    for (int k = 0; k < 10; ++k) acc[k] = wred(acc[k]);

    __shared__ float t[2][4][5];
    __shared__ float him[2][4][4];
    __shared__ float hvs[2][4][4];
    __shared__ float stats[2][2];

    if (lane == 0) {
#pragma unroll
        for (int k = 0; k < 5; ++k) { t[0][w][k] = acc[k]; t[1][w][k] = acc[5 + k]; }
#pragma unroll
        for (int f = 0; f < 4; ++f) { him[0][w][f] = hi0[f]; him[1][w][f] = hi1[f]; }
    }
    __syncthreads();

    if (tid < 8) {
        const int b = tid & 3, g = tid >> 2;
        const int i = (g == 0) ? i0 : i1;
        float xi[4] = {him[g][b][0], him[g][b][1], him[g][b][2], him[g][b][3]};
        float ssum = t[g][b][4];
        float r8[8];
#pragma unroll
        for (int k = 0; k < 4; ++k) { r8[k] = t[g][b][k]; r8[4 + k] = xi[k] * ssum; }
        float r[4];
#pragma unroll
        for (int f = 0; f < 4; ++f) {
            float sv = n1b[f];
#pragma unroll
            for (int k = 0; k < 8; ++k) sv += n1w[f * 8 + k] * r8[k];
            r[f] = eluf(sv);
        }
        const float w1d = W1[(size_t)i * G + i], b1i = b1[i];
#pragma unroll
        for (int f = 0; f < 4; ++f) {
            float sv = m1b[f];
#pragma unroll
            for (int k = 0; k < 4; ++k) sv += m1w[f * 8 + k] * r[k] + m1w[f * 8 + 4 + k] * xi[k];
            hvs[g][b][f] = eluf(eluf(sv) * w1d + b1i);
        }
    }
    __syncthreads();

    if (tid < 2) {  // BN per gene over (batch, feat) = 16 values
        const int g = tid;
        float mean = 0.f;
#pragma unroll
        for (int bb = 0; bb < 4; ++bb)
#pragma unroll
            for (int f = 0; f < 4; ++f) mean += hvs[g][bb][f];
        mean *= (1.f / 16.f);
        float var = 0.f;
#pragma unroll
        for (int bb = 0; bb < 4; ++bb)
#pragma unroll
            for (int f = 0; f < 4; ++f) { float d = hvs[g][bb][f] - mean; var += d * d; }
        var *= (1.f / 16.f);
        stats[g][0] = mean;
        stats[g][1] = rsqrtf(var + BN_EPS);
    }
    __syncthreads();

    if (tid < 8) {
        const int b = tid & 3, g = tid >> 2;
        const int i = (g == 0) ? i0 : i1;
        const float mean = stats[g][0], sc = stats[g][1];
        float hv[4];
#pragma unroll
        for (int f = 0; f < 4; ++f) hv[f] = (hvs[g][b][f] - mean) * sc;
        xfeat2[b * G + i] = make_float4(hv[0], hv[1], hv[2], hv[3]);
        a2[b * G + i] = e2w[0] * hv[0] + e2w[1] * hv[1] + e2w[2] * hv[2] + e2w[3] * hv[3];
        c2[b * G + i] = e2w[4] * hv[0] + e2w[5] * hv[1] + e2w[6] * hv[2] + e2w[7] * hv[3] + e2b[0];
    }
}

// ---------------- K2: round2. 1200 blocks, gene i = blockIdx. Writes upd2;
// scatters bs[i] = sum_b hgw@upd2[b,i] into global efeat/eh (device atomics, ~24K total).
__global__ __launch_bounds__(256)
void k_round2(const float* __restrict__ edge2,
              const float4* __restrict__ xfeat2,
              const float* __restrict__ a2, const float* __restrict__ c2,
              const float* __restrict__ n2w, const float* __restrict__ n2b,
              const float* __restrict__ m2w, const float* __restrict__ m2b,
              const float* __restrict__ hgw,
              const int* __restrict__ hn, const int* __restrict__ he,
              float4* __restrict__ upd2,
              float* __restrict__ efeat_g, int* __restrict__ eh_g) {
    const int i = blockIdx.x;
    const int tid = threadIdx.x;
    const int lane = tid & 63;
    const int w = tid >> 6;

    const float cb = c2[w * G + i];
    const float4* erow4 = (const float4*)(edge2 + (size_t)i * G);
    const float4* a4 = (const float4*)(a2 + (size_t)w * G);

    float acc0 = 0.f, acc1 = 0.f, acc2 = 0.f, acc3 = 0.f, acc4 = 0.f;
    for (int m = lane; m < 300; m += 64) {
        float ea[4], aa[4];
        *(float4*)ea = erow4[m];
        *(float4*)aa = a4[m];
#pragma unroll
        for (int s = 0; s < 4; ++s) {
            float4 xv = xfeat2[w * G + 4 * m + s];
            float sg = sigf(aa[s] + cb) * maskf(ea[s], BETA);
            acc0 += sg * xv.x;
            acc1 += sg * xv.y;
            acc2 += sg * xv.z;
            acc3 += sg * xv.w;
            acc4 += sg;
        }
    }
    acc0 = wred(acc0); acc1 = wred(acc1); acc2 = wred(acc2); acc3 = wred(acc3); acc4 = wred(acc4);

    __shared__ float t[4][5];
    __shared__ float hvs[4][4];
    __shared__ float stats[2];
    __shared__ float bsf[4];
    if (lane == 0) { t[w][0] = acc0; t[w][1] = acc1; t[w][2] = acc2; t[w][3] = acc3; t[w][4] = acc4; }
    __syncthreads();

    if (tid < 4) {
        const int b = tid;
        float4 xi4 = xfeat2[b * G + i];
        float xi[4] = {xi4.x, xi4.y, xi4.z, xi4.w};
        float ssum = t[b][4];
        float r8[8];
#pragma unroll
        for (int k = 0; k < 4; ++k) { r8[k] = t[b][k]; r8[4 + k] = xi[k] * ssum; }
        float r[4];
#pragma unroll
        for (int f = 0; f < 4; ++f) {
            float sv = n2b[f];
#pragma unroll
            for (int k = 0; k < 8; ++k) sv += n2w[f * 8 + k] * r8[k];
            r[f] = eluf(sv);
        }
#pragma unroll
        for (int f = 0; f < 4; ++f) {
            float sv = m2b[f];
#pragma unroll
            for (int k = 0; k < 4; ++k) sv += m2w[f * 8 + k] * r[k] + m2w[f * 8 + 4 + k] * xi[k];
            hvs[b][f] = eluf(sv);
        }
    }
    __syncthreads();

    if (tid == 0) {
        float mean = 0.f;
#pragma unroll
        for (int bb = 0; bb < 4; ++bb)
#pragma unroll
            for (int f = 0; f < 4; ++f) mean += hvs[bb][f];
        mean *= (1.f / 16.f);
        float var = 0.f;
#pragma unroll
        for (int bb = 0; bb < 4; ++bb)
#pragma unroll
            for (int f = 0; f < 4; ++f) { float d = hvs[bb][f] - mean; var += d * d; }
        var *= (1.f / 16.f);
        stats[0] = mean;
        stats[1] = rsqrtf(var + BN_EPS);
    }
    __syncthreads();

    if (tid < 4) {
        const int b = tid;
        const float mean = stats[0], sc = stats[1];
        float hv[4];
#pragma unroll
        for (int f = 0; f < 4; ++f) hv[f] = (hvs[b][f] - mean) * sc;
        upd2[b * G + i] = make_float4(hv[0], hv[1], hv[2], hv[3]);
        hvs[b][0] = hv[0]; hvs[b][1] = hv[1]; hvs[b][2] = hv[2]; hvs[b][3] = hv[3];
    }
    __syncthreads();

    if (tid < 4) {  // bsf[f] = sum_b hgw[f,:] @ hvs[b,:]
        const int f = tid;
        float sv = 0.f;
#pragma unroll
        for (int bb = 0; bb < 4; ++bb)
#pragma unroll
            for (int k = 0; k < 4; ++k) sv += hgw[f * 4 + k] * hvs[bb][k];
        bsf[f] = sv;
    }
    __syncthreads();

    const float v0 = bsf[0], v1 = bsf[1], v2 = bsf[2], v3 = bsf[3];
    for (int cI = tid; cI < NINC; cI += 256) {
        if (hn[cI] == i) {
            int e = he[cI];
            atomicAdd(&eh_g[e], 1);
            atomicAdd(&efeat_g[e * 4 + 0], v0);
            atomicAdd(&efeat_g[e * 4 + 1], v1);
            atomicAdd(&efeat_g[e * 4 + 2], v2);
            atomicAdd(&efeat_g[e * 4 + 3], v3);
        }
    }
}

// ---------------- K3: gather hx[i] from global efeat/eh + final MLP (round-2 proven scheme).
__global__ __launch_bounds__(256)
void k_final(const int* __restrict__ hn, const int* __restrict__ he,
             const float* __restrict__ efeat_g, const int* __restrict__ eh_g,
             const float4* __restrict__ upd2, const float* __restrict__ hgb,
             const float* __restrict__ m3w, const float* __restrict__ m3b,
             float4* __restrict__ out) {
    const int i = blockIdx.x;
    const int tid = threadIdx.x;
    const int lane = tid & 63;
    const int w = tid >> 6;

    float a0 = 0.f, a1 = 0.f, a2 = 0.f, a3 = 0.f, cf = 0.f;
    for (int cI = tid; cI < NINC; cI += 256) {
        if (hn[cI] == i) {
            int e = he[cI];
            float binv = 0.25f / (float)eh_g[e];  // bdeg = BSZ * hist(edges)
            a0 += efeat_g[e * 4 + 0] * binv;
            a1 += efeat_g[e * 4 + 1] * binv;
            a2 += efeat_g[e * 4 + 2] * binv;
            a3 += efeat_g[e * 4 + 3] * binv;
            cf += 1.f;
        }
    }
    a0 = wred(a0); a1 = wred(a1); a2 = wred(a2); a3 = wred(a3); cf = wred(cf);
    __shared__ float red[4][5];
    if (lane == 0) { red[w][0] = a0; red[w][1] = a1; red[w][2] = a2; red[w][3] = a3; red[w][4] = cf; }
    __syncthreads();

    if (tid < 4) {
        const int b = tid;
        float dg = red[0][4] + red[1][4] + red[2][4] + red[3][4];
        float dinv = dg > 0.f ? 1.f / dg : 0.f;
        float hxp[4];
#pragma unroll
        for (int f = 0; f < 4; ++f) {
            float hx = (red[0][f] + red[1][f] + red[2][f] + red[3][f]) * dinv;
            hxp[f] = eluf(hx + hgb[f]);
        }
        float4 u4 = upd2[b * G + i];
        float u[4] = {u4.x, u4.y, u4.z, u4.w};
        float o4[4];
#pragma unroll
        for (int f = 0; f < 4; ++f) {
            float sv = m3b[f];
#pragma unroll
            for (int k = 0; k < 4; ++k)
                sv += m3w[f * 8 + k] * u[k] + m3w[f * 8 + 4 + k] * hxp[k];
            o4[f] = eluf(sv);
        }
        out[b * G + i] = make_float4(o4[0], o4[1], o4[2], o4[3]);
    }
}

extern "C" void kernel_launch(void* const* d_in, const int* in_sizes, int n_in,
                              void* d_out, int out_size, void* d_ws, size_t ws_size,
                              hipStream_t stream) {
    const float* x       = (const float*)d_in[0];
    const float* edge1   = (const float*)d_in[1];
    const float* edge2   = (const float*)d_in[2];
    const float* W1      = (const float*)d_in[3];
    const float* b1      = (const float*)d_in[4];
    const float* infer_w = (const float*)d_in[5];
    const float* infer_b = (const float*)d_in[6];
    const float* e1w     = (const float*)d_in[7];
    const float* e1b     = (const float*)d_in[8];
    const float* e2w     = (const float*)d_in[9];
    const float* e2b     = (const float*)d_in[10];
    const float* n1w     = (const float*)d_in[11];
    const float* n1b     = (const float*)d_in[12];
    const float* n2w     = (const float*)d_in[13];
    const float* n2b     = (const float*)d_in[14];
    const float* m1w     = (const float*)d_in[15];
    const float* m1b     = (const float*)d_in[16];
    const float* m2w     = (const float*)d_in[17];
    const float* m2b     = (const float*)d_in[18];
    const float* m3w     = (const float*)d_in[19];
    const float* m3b     = (const float*)d_in[20];
    const float* hgw     = (const float*)d_in[21];
    const float* hgb     = (const float*)d_in[22];
    const int*   hn      = (const int*)d_in[23];
    const int*   he      = (const int*)d_in[24];

    char* ws = (char*)d_ws;
    float4* xfeat2 = (float4*)(ws + 0);       // 76800
    float4* upd2   = (float4*)(ws + 76800);   // 76800
    float*  a2     = (float*)(ws + 153600);   // 19200
    float*  c2     = (float*)(ws + 172800);   // 19200
    float*  efeat  = (float*)(ws + 192000);   // 1200 f32 = 4800
    int*    eh     = (int*)(ws + 196800);     // 300 i32 = 1200
    // efeat+eh contiguous: zeroed as 1500 words by k_round1 block 0

    k_round1<<<600, 256, 0, stream>>>(x, edge1, W1, b1, infer_w, infer_b, e1w, e1b,
                                      n1w, n1b, m1w, m1b, e2w, e2b, xfeat2, a2, c2,
                                      (int*)efeat);
    k_round2<<<1200, 256, 0, stream>>>(edge2, xfeat2, a2, c2, n2w, n2b, m2w, m2b, hgw,
                                       hn, he, upd2, efeat, eh);
    k_final<<<1200, 256, 0, stream>>>(hn, he, efeat, eh, upd2, hgb, m3w, m3b,
                                      (float4*)d_out);
}